// Round 10
// baseline (67.353 us; speedup 1.0000x reference)
//
#include <hip/hip_runtime.h>
#include <hip/hip_bf16.h>
#include <math.h>

#define BATCH 16384
#define OUTF  1024
#define INF   1024
#define KPROJ 256
#define MTOT  (BATCH + OUTF)   // 17408

#define GBM 32
#define GBN 128
#define GBK 64
#define NKT (INF / GBK)        // 16
#define NWG ((MTOT / GBM) * 2) // 1088 (% 8 == 0)

#define NZ_THRESH 0.15f        // ~6.8 sigma of f16 dot error (sigma ~0.022)

typedef unsigned int       u32;
typedef unsigned long long u64;
typedef unsigned short     u16;
typedef _Float16           f16;
typedef __attribute__((ext_vector_type(8))) _Float16 f16x8;
typedef __attribute__((ext_vector_type(4))) float    f32x4;

#define SCHED0() __builtin_amdgcn_sched_barrier(0)

__device__ __forceinline__ void gl_lds16(const void* g, void* l) {
    __builtin_amdgcn_global_load_lds(
        (const __attribute__((address_space(1))) u32*)g,
        (__attribute__((address_space(3))) u32*)l, 16, 0, 0);
}

// ---------------------------------------------------------------------------
// prep_p: convert P (256 rows x 1024) fp32 -> f16 (RN). One wave per row.
// ---------------------------------------------------------------------------
__global__ __launch_bounds__(256) void prep_p(const float* __restrict__ P,
                                              f16* __restrict__ Bp) {
    const int wave = threadIdx.x >> 6, lane = threadIdx.x & 63;
    const int pr = blockIdx.x * 4 + wave;             // 0..255
    const float4* v = (const float4*)(P + (size_t)pr * INF);
    ushort4* d = (ushort4*)(Bp + (size_t)pr * INF);
#pragma unroll
    for (int q = 0; q < 4; ++q) {
        float4 f = v[lane + 64 * q];
        ushort4 o;
        o.x = __builtin_bit_cast(u16, (f16)f.x);
        o.y = __builtin_bit_cast(u16, (f16)f.y);
        o.z = __builtin_bit_cast(u16, (f16)f.z);
        o.w = __builtin_bit_cast(u16, (f16)f.w);
        d[lane + 64 * q] = o;
    }
}

// ---------------------------------------------------------------------------
// f16 MFMA sign GEMM — R8 body + GROUPED A FETCH (DRAM-pattern fix).
// Theory: every prior variant fetched A as 256 B/row/K-step; ~1000s of
// concurrent 256 B streams at 4 KB stride page-miss on nearly every DRAM
// access, capping effective HBM BW at ~1.4 TB/s (the invariant ~47 us).
// Now A is fetched 4 K-steps at a time: each thread issues 8 back-to-back
// float4, so each row is read in ONE 1 KB contiguous window (4x coarser).
// Double-banked A regs (qa/qb) give the group a 4-step issue->use lead.
// ldsB is double-buffered; B(s+1) issued after barrier1(s).
// In-order vmcnt queue per step s (issues during step s-1's compute):
//   s%4==1 : [B(s)4, Agrp8] -> vmcnt(8) drains B, keeps A in flight
//   else   : [maybe Agrp (>=1.7 steps old), B(s)4] -> vmcnt(0) (== R8 today)
//   s==13  : no A-group was issued at s==12 -> vmcnt(0)
// Epilogue (fused fp64 fixup, ballot pack, norms) identical to R8.
// ---------------------------------------------------------------------------
__global__ __launch_bounds__(256, 3) void gemm_signs(const float* __restrict__ X,
                                                     const float* __restrict__ W,
                                                     const f16* __restrict__ Bp,
                                                     const float* __restrict__ Pf,
                                                     u64* __restrict__ cx,
                                                     u64* __restrict__ cw,
                                                     float* __restrict__ xn,
                                                     float* __restrict__ wn) {
    __shared__ __align__(16) unsigned char ldsA[GBM * 8 * 16];        //  4 KB
    __shared__ __align__(16) unsigned char ldsB[2 * GBN * 8 * 16];    // 32 KB
    __shared__ u16 sw[GBM][8];
    __shared__ float nsq[GBM][8];

    const int t    = threadIdx.x;
    const int wid  = t >> 6, lane = t & 63;
    const int l4   = lane >> 4, l15 = lane & 15;
    const int wc   = wid;                       // 4 waves across N
    // XCD-aware bijective swizzle (1088 = 8 * 136); column halves of a
    // row-tile land on the same XCD -> A-tile shared in that L2 (R8 win).
    const int sb   = (blockIdx.x & 7) * (NWG / 8) + (blockIdx.x >> 3);
    const int bm   = sb >> 1;
    const int bn0  = (sb & 1) * GBN;
    const int am0  = bm * GBM;

    // A staging map: thread t -> chunk ca of row ra, LDS slot t
    const int ra = t >> 3, sa = t & 7, ca = sa ^ (ra & 7);
    const float* Asrc = (am0 < BATCH) ? X + (size_t)am0 * INF
                                      : W + (size_t)(am0 - BATCH) * INF;
    const float* aRow = Asrc + (size_t)ra * INF + ca * 8;

    // B staging map (global_load_lds): wave wid, rep i covers linear chunks
    const f16* bsrc[4];
#pragma unroll
    for (int i = 0; i < 4; ++i) {
        const int g = (i * 4 + wid) * 64 + lane;
        const int row = g >> 3, sl = g & 7, cb = sl ^ (row & 7);
        bsrc[i] = Bp + (size_t)(bn0 + row) * INF + cb * 8;
    }

    f32x4 acc[2][2] = {};
    float ssq = 0.0f;
    float4 qa0, qa1, qa2, qa3, qa4, qa5, qa6, qa7;
    float4 qb0, qb1, qb2, qb3, qb4, qb5, qb6, qb7;

// 8 back-to-back float4: row's 1 KB window [G*256 .. G*256+255] floats
#define ALOAD_G(P, G)                                                         \
    P##0 = *(const float4*)(aRow + ((G) * 4 + 0) * 64);                       \
    P##1 = *(const float4*)(aRow + ((G) * 4 + 0) * 64 + 4);                   \
    P##2 = *(const float4*)(aRow + ((G) * 4 + 1) * 64);                       \
    P##3 = *(const float4*)(aRow + ((G) * 4 + 1) * 64 + 4);                   \
    P##4 = *(const float4*)(aRow + ((G) * 4 + 2) * 64);                       \
    P##5 = *(const float4*)(aRow + ((G) * 4 + 2) * 64 + 4);                   \
    P##6 = *(const float4*)(aRow + ((G) * 4 + 3) * 64);                       \
    P##7 = *(const float4*)(aRow + ((G) * 4 + 3) * 64 + 4);

#define ASTAGE(Q0, Q1)                                                        \
    {                                                                         \
        ssq += Q0.x * Q0.x + Q0.y * Q0.y + Q0.z * Q0.z + Q0.w * Q0.w +        \
               Q1.x * Q1.x + Q1.y * Q1.y + Q1.z * Q1.z + Q1.w * Q1.w;         \
        f16x8 h;                                                              \
        h[0] = (f16)Q0.x; h[1] = (f16)Q0.y; h[2] = (f16)Q0.z; h[3] = (f16)Q0.w;\
        h[4] = (f16)Q1.x; h[5] = (f16)Q1.y; h[6] = (f16)Q1.z; h[7] = (f16)Q1.w;\
        *(f16x8*)(ldsA + t * 16) = h;                                         \
    }

#define BISSUE(S1)                                                            \
    {                                                                         \
        _Pragma("unroll")                                                     \
        for (int i = 0; i < 4; ++i)                                           \
            gl_lds16(bsrc[i] + (S1) * GBK,                                    \
                     ldsB + ((S1) & 1) * 16384 + (i * 4 + wid) * 1024);       \
    }

#define COMPUTE(BOFF)                                                         \
    {                                                                         \
        _Pragma("unroll")                                                     \
        for (int ks = 0; ks < 2; ++ks) {                                      \
            f16x8 af[2], bf[2];                                               \
            _Pragma("unroll")                                                 \
            for (int i = 0; i < 2; ++i) {                                     \
                const int row = i * 16 + l15;                                 \
                const int slot = (ks * 4 + l4) ^ (row & 7);                   \
                af[i] = *(const f16x8*)(ldsA + row * 128 + slot * 16);        \
            }                                                                 \
            _Pragma("unroll")                                                 \
            for (int j = 0; j < 2; ++j) {                                     \
                const int col = wc * 32 + j * 16 + l15;                       \
                const int slot = (ks * 4 + l4) ^ (col & 7);                   \
                bf[j] = *(const f16x8*)(ldsB + (BOFF) + col * 128 + slot * 16);\
            }                                                                 \
            _Pragma("unroll")                                                 \
            for (int i = 0; i < 2; ++i)                                       \
                _Pragma("unroll")                                             \
                for (int j = 0; j < 2; ++j)                                   \
                    acc[i][j] = __builtin_amdgcn_mfma_f32_16x16x32_f16(       \
                        af[i], bf[j], acc[i][j], 0, 0, 0);                    \
        }                                                                     \
    }

// step with B-issue and optional A-group issue
#define GSTEP_A(S, Q0, Q1, VM, AP, AG)                                        \
    ASTAGE(Q0, Q1); SCHED0();                                                 \
    asm volatile("s_waitcnt vmcnt(" VM ") lgkmcnt(0)" ::: "memory"); SCHED0();\
    __builtin_amdgcn_s_barrier(); SCHED0();                                   \
    BISSUE((S) + 1); SCHED0();                                                \
    ALOAD_G(AP, AG); SCHED0();                                                \
    COMPUTE(((S) & 1) * 16384); SCHED0();                                     \
    __builtin_amdgcn_s_barrier(); SCHED0();

#define GSTEP_B(S, Q0, Q1, VM)                                                \
    ASTAGE(Q0, Q1); SCHED0();                                                 \
    asm volatile("s_waitcnt vmcnt(" VM ") lgkmcnt(0)" ::: "memory"); SCHED0();\
    __builtin_amdgcn_s_barrier(); SCHED0();                                   \
    BISSUE((S) + 1); SCHED0();                                                \
    COMPUTE(((S) & 1) * 16384); SCHED0();                                     \
    __builtin_amdgcn_s_barrier(); SCHED0();

#define GSTEP_N(S, Q0, Q1, VM)                                                \
    ASTAGE(Q0, Q1); SCHED0();                                                 \
    asm volatile("s_waitcnt vmcnt(" VM ") lgkmcnt(0)" ::: "memory"); SCHED0();\
    __builtin_amdgcn_s_barrier(); SCHED0();                                   \
    COMPUTE(((S) & 1) * 16384); SCHED0();                                     \
    __builtin_amdgcn_s_barrier(); SCHED0();

    // prologue: B(0) first (oldest in queue), then A group 0
    BISSUE(0);
    ALOAD_G(qa, 0);
    SCHED0();

    GSTEP_A(0,  qa0, qa1, "0", qb, 1);
    GSTEP_B(1,  qa2, qa3, "8");
    GSTEP_B(2,  qa4, qa5, "0");
    GSTEP_B(3,  qa6, qa7, "0");
    GSTEP_A(4,  qb0, qb1, "0", qa, 2);
    GSTEP_B(5,  qb2, qb3, "8");
    GSTEP_B(6,  qb4, qb5, "0");
    GSTEP_B(7,  qb6, qb7, "0");
    GSTEP_A(8,  qa0, qa1, "0", qb, 3);
    GSTEP_B(9,  qa2, qa3, "8");
    GSTEP_B(10, qa4, qa5, "0");
    GSTEP_B(11, qa6, qa7, "0");
    GSTEP_B(12, qb0, qb1, "0");
    GSTEP_B(13, qb2, qb3, "0");
    GSTEP_B(14, qb4, qb5, "0");
    GSTEP_N(15, qb6, qb7, "0");

    nsq[ra][sa] = ssq;

    // epilogue: fused fp64 fixup for near-zero dots, then ballot sign-pack.
    // C layout: local row = i*16 + l4*4 + q, col = bn0 + wc*32 + j*16 + l15.
#pragma unroll
    for (int i = 0; i < 2; ++i)
#pragma unroll
        for (int j = 0; j < 2; ++j)
#pragma unroll
            for (int q = 0; q < 4; ++q) {
                const float v = acc[i][j][q];
                int bit = (v >= 0.0f) ? 1 : 0;
                u64 fl = __ballot(fabsf(v) < NZ_THRESH);
                while (fl) {   // rare (~4/wave): whole wave re-dots in fp64
                    const int src = __ffsll((long long)fl) - 1;
                    fl &= fl - 1;
                    const int lrow = i * 16 + ((src >> 4) << 2) + q;
                    const int col  = bn0 + wc * 32 + j * 16 + (src & 15);
                    const float* xr = Asrc + (size_t)lrow * INF + lane * 16;
                    const float* pr = Pf + (size_t)col * INF + lane * 16;
                    double s = 0.0;
#pragma unroll
                    for (int c4 = 0; c4 < 4; ++c4) {
                        float4 xa = *(const float4*)(xr + c4 * 4);
                        float4 pa = *(const float4*)(pr + c4 * 4);
                        s += (double)xa.x * pa.x + (double)xa.y * pa.y +
                             (double)xa.z * pa.z + (double)xa.w * pa.w;
                    }
#pragma unroll
                    for (int off = 32; off; off >>= 1) s += __shfl_xor(s, off, 64);
                    if (lane == src) bit = (s >= 0.0) ? 1 : 0;
                }
                const u64 b = __ballot(bit != 0);
                if (l15 == 0)
                    sw[i * 16 + l4 * 4 + q][wc * 2 + j] = (u16)(b >> (l4 * 16));
            }
    if (bn0 == 0 && t < GBM) {   // fused norm write (one block-column only)
        const float* p = nsq[t];
        float s = ((p[0] + p[1]) + (p[2] + p[3])) + ((p[4] + p[5]) + (p[6] + p[7]));
        const float n = sqrtf(s) + 1.1920929e-07f;
        const int grow = am0 + t;
        if (grow < BATCH) xn[grow] = n; else wn[grow - BATCH] = n;
    }
    __syncthreads();
    if (t < 64) {
        const int r = t >> 1, wsel = t & 1;
        const u64 val = *(const u64*)&sw[r][wsel * 4];
        const int grow = am0 + r;
        const int word = (sb & 1) * 2 + wsel;
        if (grow < BATCH) cx[(size_t)grow * 4 + word] = val;
        else              cw[(size_t)(grow - BATCH) * 4 + word] = val;
    }
}

// ---------------------------------------------------------------------------
// out[b][m] = xn[b] * wn[m] * cos(pi * popc / 256)
// ---------------------------------------------------------------------------
__global__ __launch_bounds__(256) void popc_out(const u64* __restrict__ cx,
                                                const u64* __restrict__ cw,
                                                const float* __restrict__ xn,
                                                const float* __restrict__ wn,
                                                float* __restrict__ out) {
    __shared__ float lut[257];
    __shared__ u64 cxs[64][4];
    __shared__ float xns[64];
    const int t = threadIdx.x;

    lut[t] = (float)cos((double)t * (3.14159265358979323846 / 256.0));
    if (t == 0) lut[256] = -1.0f;

    const int r0 = blockIdx.x * 64;
    cxs[t >> 2][t & 3] = cx[(size_t)r0 * 4 + t];
    if (t < 64) xns[t] = xn[r0 + t];

    const ulonglong4* cwv4 = (const ulonglong4*)cw;
    ulonglong4 c0 = cwv4[4 * t + 0];
    ulonglong4 c1 = cwv4[4 * t + 1];
    ulonglong4 c2 = cwv4[4 * t + 2];
    ulonglong4 c3 = cwv4[4 * t + 3];
    float4 wnr = ((const float4*)wn)[t];

    __syncthreads();

    float4* outv = (float4*)out;
    const size_t obase = (size_t)r0 * (OUTF / 4) + t;
#pragma unroll 4
    for (int r = 0; r < 64; ++r) {
        const u64 a0 = cxs[r][0], a1 = cxs[r][1], a2 = cxs[r][2], a3 = cxs[r][3];
        const float sx = xns[r];
        float4 o;
        o.x = sx * wnr.x * lut[__popcll(a0 ^ c0.x) + __popcll(a1 ^ c0.y) +
                               __popcll(a2 ^ c0.z) + __popcll(a3 ^ c0.w)];
        o.y = sx * wnr.y * lut[__popcll(a0 ^ c1.x) + __popcll(a1 ^ c1.y) +
                               __popcll(a2 ^ c1.z) + __popcll(a3 ^ c1.w)];
        o.z = sx * wnr.z * lut[__popcll(a0 ^ c2.x) + __popcll(a1 ^ c2.y) +
                               __popcll(a2 ^ c2.z) + __popcll(a3 ^ c2.w)];
        o.w = sx * wnr.w * lut[__popcll(a0 ^ c3.x) + __popcll(a1 ^ c3.y) +
                               __popcll(a2 ^ c3.z) + __popcll(a3 ^ c3.w)];
        outv[obase + (size_t)r * (OUTF / 4)] = o;
    }
}

extern "C" void kernel_launch(void* const* d_in, const int* in_sizes, int n_in,
                              void* d_out, int out_size, void* d_ws, size_t ws_size,
                              hipStream_t stream) {
    const float* x = (const float*)d_in[0];
    const float* w = (const float*)d_in[1];
    const float* P = (const float*)d_in[2];
    float* out = (float*)d_out;

    char* ws = (char*)d_ws;
    f16*  Bp = (f16*)ws;                         // +0        (524288 B)
    u64*  cx = (u64*)(ws + 524288);              // +524288   (524288 B)
    u64*  cw = (u64*)(ws + 1048576);             // +1048576  (32768 B)
    float* xn = (float*)(ws + 1081344);          // +1081344  (65536 B)
    float* wn = (float*)(ws + 1146880);          // +1146880  (4096 B)

    prep_p<<<KPROJ / 4, 256, 0, stream>>>(P, Bp);

    gemm_signs<<<NWG, 256, 0, stream>>>(x, w, Bp, P, cx, cw, xn, wn);

    popc_out<<<BATCH / 64, 256, 0, stream>>>(cx, cw, xn, wn, out);
}

// Round 11
// 61.668 us; speedup vs baseline: 1.0922x; 1.0922x over previous
//
#include <hip/hip_runtime.h>
#include <hip/hip_bf16.h>
#include <math.h>

#define BATCH 16384
#define OUTF  1024
#define INF   1024
#define KPROJ 256
#define MTOT  (BATCH + OUTF)   // 17408

#define GBM 64
#define GBN 128
#define GBK 64
#define NKT (INF / GBK)        // 16
#define NWG ((MTOT / GBM) * 2) // 544 blocks (544 % 8 == 0)

#define NZ_THRESH 0.15f        // ~6.8 sigma of f16 dot error (sigma ~0.022)

typedef unsigned int       u32;
typedef unsigned long long u64;
typedef unsigned short     u16;
typedef _Float16           f16;
typedef __attribute__((ext_vector_type(8))) _Float16 f16x8;
typedef __attribute__((ext_vector_type(4))) float    f32x4;

#define SCHED0() __builtin_amdgcn_sched_barrier(0)

__device__ __forceinline__ void gl_lds16(const void* g, void* l) {
    __builtin_amdgcn_global_load_lds(
        (const __attribute__((address_space(1))) u32*)g,
        (__attribute__((address_space(3))) u32*)l, 16, 0, 0);
}

// ---------------------------------------------------------------------------
// prep_p: convert P (256 rows x 1024) fp32 -> f16 (RN). One wave per row.
// ---------------------------------------------------------------------------
__global__ __launch_bounds__(256) void prep_p(const float* __restrict__ P,
                                              f16* __restrict__ Bp) {
    const int wave = threadIdx.x >> 6, lane = threadIdx.x & 63;
    const int pr = blockIdx.x * 4 + wave;             // 0..255
    const float4* v = (const float4*)(P + (size_t)pr * INF);
    ushort4* d = (ushort4*)(Bp + (size_t)pr * INF);
#pragma unroll
    for (int q = 0; q < 4; ++q) {
        float4 f = v[lane + 64 * q];
        ushort4 o;
        o.x = __builtin_bit_cast(u16, (f16)f.x);
        o.y = __builtin_bit_cast(u16, (f16)f.y);
        o.z = __builtin_bit_cast(u16, (f16)f.z);
        o.w = __builtin_bit_cast(u16, (f16)f.w);
        d[lane + 64 * q] = o;
    }
}

// ---------------------------------------------------------------------------
// f16 MFMA sign GEMM — the session's best verified kernel (R9, 61.68 us).
// 2-barrier K-loop, global_load_lds B staging, A reg-prefetch kept in
// flight across the barrier via counted vmcnt(4), XCD-aware bijective block
// swizzle (the one measured win: co-locates a row-tile's two column-halves
// on one XCD's L2, FETCH 97 -> 61 MB), GBM=64.
// Ceiling note: per-block K-loop time D ~ 43-46 us is invariant across
// pipeline depth, occupancy, tile size, decorrelation, nt-hints, epilogue
// extraction, and A-fetch granularity (rounds 1-10); only total-byte cuts
// moved it.  Makespan ~ D at this grid; further gains need a mechanism not
// expressible at this source level (per-step latency under ~1000 lockstep
// tile streams).
// ---------------------------------------------------------------------------
__global__ __launch_bounds__(256, 4) void gemm_signs(const float* __restrict__ X,
                                                     const float* __restrict__ W,
                                                     const f16* __restrict__ Bp,
                                                     const float* __restrict__ Pf,
                                                     u64* __restrict__ cx,
                                                     u64* __restrict__ cw,
                                                     float* __restrict__ xn,
                                                     float* __restrict__ wn) {
    __shared__ __align__(16) unsigned char ldsA[GBM * 8 * 16];    //  8 KB
    __shared__ __align__(16) unsigned char ldsB[GBN * 8 * 16];    // 16 KB
    __shared__ u16 sw[GBM][8];
    __shared__ float nsq[GBM][8];

    const int t    = threadIdx.x;
    const int wid  = t >> 6, lane = t & 63;
    const int l4   = lane >> 4, l15 = lane & 15;
    const int wc   = wid;                       // 4 waves across N
    // XCD-aware bijective swizzle: NWG = 544 = 8 * 68; column halves
    // sb=2m,2m+1 map to physical b,b+8 (same XCD chunk -> shared A in L2)
    const int sb   = (blockIdx.x & 7) * (NWG / 8) + (blockIdx.x >> 3);
    const int bm   = sb >> 1;
    const int bn0  = (sb & 1) * GBN;
    const int am0  = bm * GBM;

    // A staging map: thread t -> chunk ca of rows ra and ra+32 (same &7 ->
    // same swizzled chunk), written at linear slots t and t+256.
    const int ra = t >> 3, sa = t & 7, ca = sa ^ (ra & 7);
    const float* Asrc = (am0 < BATCH) ? X + (size_t)am0 * INF
                                      : W + (size_t)(am0 - BATCH) * INF;
    const float* aRow0 = Asrc + (size_t)ra * INF + ca * 8;
    const float* aRow1 = aRow0 + (size_t)32 * INF;

    // B staging map (global_load_lds): wave wid, rep i covers linear chunks
    const f16* bsrc[4];
#pragma unroll
    for (int i = 0; i < 4; ++i) {
        const int g = (i * 4 + wid) * 64 + lane;
        const int row = g >> 3, sl = g & 7, cb = sl ^ (row & 7);
        bsrc[i] = Bp + (size_t)(bn0 + row) * INF + cb * 8;
    }

    f32x4 acc[4][2] = {};
    float ssq0 = 0.0f, ssq1 = 0.0f;
    float4 pf0 = *(const float4*)(aRow0);
    float4 pf1 = *(const float4*)(aRow0 + 4);
    float4 pf2 = *(const float4*)(aRow1);
    float4 pf3 = *(const float4*)(aRow1 + 4);

    for (int kt = 0; kt < NKT; ++kt) {
        // ---- STAGE ----
        ssq0 += pf0.x * pf0.x + pf0.y * pf0.y + pf0.z * pf0.z + pf0.w * pf0.w +
                pf1.x * pf1.x + pf1.y * pf1.y + pf1.z * pf1.z + pf1.w * pf1.w;
        ssq1 += pf2.x * pf2.x + pf2.y * pf2.y + pf2.z * pf2.z + pf2.w * pf2.w +
                pf3.x * pf3.x + pf3.y * pf3.y + pf3.z * pf3.z + pf3.w * pf3.w;
        {
            f16x8 h0, h1;
            h0[0] = (f16)pf0.x; h0[1] = (f16)pf0.y; h0[2] = (f16)pf0.z; h0[3] = (f16)pf0.w;
            h0[4] = (f16)pf1.x; h0[5] = (f16)pf1.y; h0[6] = (f16)pf1.z; h0[7] = (f16)pf1.w;
            h1[0] = (f16)pf2.x; h1[1] = (f16)pf2.y; h1[2] = (f16)pf2.z; h1[3] = (f16)pf2.w;
            h1[4] = (f16)pf3.x; h1[5] = (f16)pf3.y; h1[6] = (f16)pf3.z; h1[7] = (f16)pf3.w;
            *(f16x8*)(ldsA + t * 16) = h0;
            *(f16x8*)(ldsA + 4096 + t * 16) = h1;
        }
#pragma unroll
        for (int i = 0; i < 4; ++i)
            gl_lds16(bsrc[i] + kt * GBK, ldsB + (i * 4 + wid) * 1024);
        SCHED0();
        if (kt + 1 < NKT) {   // A prefetch for kt+1 stays in flight across barrier
            pf0 = *(const float4*)(aRow0 + (kt + 1) * GBK);
            pf1 = *(const float4*)(aRow0 + (kt + 1) * GBK + 4);
            pf2 = *(const float4*)(aRow1 + (kt + 1) * GBK);
            pf3 = *(const float4*)(aRow1 + (kt + 1) * GBK + 4);
            SCHED0();
            asm volatile("s_waitcnt vmcnt(4) lgkmcnt(0)" ::: "memory");
        } else {
            asm volatile("s_waitcnt vmcnt(0) lgkmcnt(0)" ::: "memory");
        }
        SCHED0();
        __builtin_amdgcn_s_barrier();
        SCHED0();
        // ---- COMPUTE ----
#pragma unroll
        for (int ks = 0; ks < 2; ++ks) {
            f16x8 af[4], bf[2];
#pragma unroll
            for (int i = 0; i < 4; ++i) {
                const int row = i * 16 + l15;
                const int slot = (ks * 4 + l4) ^ (row & 7);
                af[i] = *(const f16x8*)(ldsA + row * 128 + slot * 16);
            }
#pragma unroll
            for (int j = 0; j < 2; ++j) {
                const int col = wc * 32 + j * 16 + l15;
                const int slot = (ks * 4 + l4) ^ (col & 7);
                bf[j] = *(const f16x8*)(ldsB + col * 128 + slot * 16);
            }
#pragma unroll
            for (int i = 0; i < 4; ++i)
#pragma unroll
                for (int j = 0; j < 2; ++j)
                    acc[i][j] = __builtin_amdgcn_mfma_f32_16x16x32_f16(af[i], bf[j], acc[i][j], 0, 0, 0);
        }
        SCHED0();
        __builtin_amdgcn_s_barrier();
        SCHED0();
    }

    nsq[ra][sa]      = ssq0;
    nsq[ra + 32][sa] = ssq1;

    // epilogue: fused fp64 fixup for near-zero dots, then ballot sign-pack.
    // C layout: local row = i*16 + l4*4 + q, col = bn0 + wc*32 + j*16 + l15.
#pragma unroll
    for (int i = 0; i < 4; ++i)
#pragma unroll
        for (int j = 0; j < 2; ++j)
#pragma unroll
            for (int q = 0; q < 4; ++q) {
                const float v = acc[i][j][q];
                int bit = (v >= 0.0f) ? 1 : 0;
                u64 fl = __ballot(fabsf(v) < NZ_THRESH);
                while (fl) {   // rare (~8/wave): whole wave re-dots in fp64
                    const int src = __ffsll((long long)fl) - 1;
                    fl &= fl - 1;
                    const int lrow = i * 16 + ((src >> 4) << 2) + q;
                    const int col  = bn0 + wc * 32 + j * 16 + (src & 15);
                    const float* xr = Asrc + (size_t)lrow * INF + lane * 16;
                    const float* pr = Pf + (size_t)col * INF + lane * 16;
                    double s = 0.0;
#pragma unroll
                    for (int c4 = 0; c4 < 4; ++c4) {
                        float4 xa = *(const float4*)(xr + c4 * 4);
                        float4 pa = *(const float4*)(pr + c4 * 4);
                        s += (double)xa.x * pa.x + (double)xa.y * pa.y +
                             (double)xa.z * pa.z + (double)xa.w * pa.w;
                    }
#pragma unroll
                    for (int off = 32; off; off >>= 1) s += __shfl_xor(s, off, 64);
                    if (lane == src) bit = (s >= 0.0) ? 1 : 0;
                }
                const u64 b = __ballot(bit != 0);
                if (l15 == 0)
                    sw[i * 16 + l4 * 4 + q][wc * 2 + j] = (u16)(b >> (l4 * 16));
            }
    if (bn0 == 0 && t < GBM) {   // fused norm write (one block-column only)
        const float* p = nsq[t];
        float s = ((p[0] + p[1]) + (p[2] + p[3])) + ((p[4] + p[5]) + (p[6] + p[7]));
        const float n = sqrtf(s) + 1.1920929e-07f;
        const int grow = am0 + t;
        if (grow < BATCH) xn[grow] = n; else wn[grow - BATCH] = n;
    }
    __syncthreads();
    if (t < 128) {
        const int r = t >> 1, wsel = t & 1;
        const u64 val = *(const u64*)&sw[r][wsel * 4];
        const int grow = am0 + r;
        const int word = (sb & 1) * 2 + wsel;
        if (grow < BATCH) cx[(size_t)grow * 4 + word] = val;
        else              cw[(size_t)(grow - BATCH) * 4 + word] = val;
    }
}

// ---------------------------------------------------------------------------
// out[b][m] = xn[b] * wn[m] * cos(pi * popc / 256)
// ---------------------------------------------------------------------------
__global__ __launch_bounds__(256) void popc_out(const u64* __restrict__ cx,
                                                const u64* __restrict__ cw,
                                                const float* __restrict__ xn,
                                                const float* __restrict__ wn,
                                                float* __restrict__ out) {
    __shared__ float lut[257];
    __shared__ u64 cxs[64][4];
    __shared__ float xns[64];
    const int t = threadIdx.x;

    lut[t] = (float)cos((double)t * (3.14159265358979323846 / 256.0));
    if (t == 0) lut[256] = -1.0f;

    const int r0 = blockIdx.x * 64;
    cxs[t >> 2][t & 3] = cx[(size_t)r0 * 4 + t];
    if (t < 64) xns[t] = xn[r0 + t];

    const ulonglong4* cwv4 = (const ulonglong4*)cw;
    ulonglong4 c0 = cwv4[4 * t + 0];
    ulonglong4 c1 = cwv4[4 * t + 1];
    ulonglong4 c2 = cwv4[4 * t + 2];
    ulonglong4 c3 = cwv4[4 * t + 3];
    float4 wnr = ((const float4*)wn)[t];

    __syncthreads();

    float4* outv = (float4*)out;
    const size_t obase = (size_t)r0 * (OUTF / 4) + t;
#pragma unroll 4
    for (int r = 0; r < 64; ++r) {
        const u64 a0 = cxs[r][0], a1 = cxs[r][1], a2 = cxs[r][2], a3 = cxs[r][3];
        const float sx = xns[r];
        float4 o;
        o.x = sx * wnr.x * lut[__popcll(a0 ^ c0.x) + __popcll(a1 ^ c0.y) +
                               __popcll(a2 ^ c0.z) + __popcll(a3 ^ c0.w)];
        o.y = sx * wnr.y * lut[__popcll(a0 ^ c1.x) + __popcll(a1 ^ c1.y) +
                               __popcll(a2 ^ c1.z) + __popcll(a3 ^ c1.w)];
        o.z = sx * wnr.z * lut[__popcll(a0 ^ c2.x) + __popcll(a1 ^ c2.y) +
                               __popcll(a2 ^ c2.z) + __popcll(a3 ^ c2.w)];
        o.w = sx * wnr.w * lut[__popcll(a0 ^ c3.x) + __popcll(a1 ^ c3.y) +
                               __popcll(a2 ^ c3.z) + __popcll(a3 ^ c3.w)];
        outv[obase + (size_t)r * (OUTF / 4)] = o;
    }
}

extern "C" void kernel_launch(void* const* d_in, const int* in_sizes, int n_in,
                              void* d_out, int out_size, void* d_ws, size_t ws_size,
                              hipStream_t stream) {
    const float* x = (const float*)d_in[0];
    const float* w = (const float*)d_in[1];
    const float* P = (const float*)d_in[2];
    float* out = (float*)d_out;

    char* ws = (char*)d_ws;
    f16*  Bp = (f16*)ws;                         // +0        (524288 B)
    u64*  cx = (u64*)(ws + 524288);              // +524288   (524288 B)
    u64*  cw = (u64*)(ws + 1048576);             // +1048576  (32768 B)
    float* xn = (float*)(ws + 1081344);          // +1081344  (65536 B)
    float* wn = (float*)(ws + 1146880);          // +1146880  (4096 B)

    prep_p<<<KPROJ / 4, 256, 0, stream>>>(P, Bp);

    gemm_signs<<<NWG, 256, 0, stream>>>(x, w, Bp, P, cx, cw, xn, wn);

    popc_out<<<BATCH / 64, 256, 0, stream>>>(cx, cw, xn, wn, out);
}